// Round 3
// baseline (897.331 us; speedup 1.0000x reference)
//
#include <hip/hip_runtime.h>

#define E_EDGES 500000
#define N_NODES 30000
#define H_DIM   256

typedef float  floatx4 __attribute__((ext_vector_type(4)));
typedef short  shortx4 __attribute__((ext_vector_type(4)));
typedef short  shortx8 __attribute__((ext_vector_type(8)));
typedef __bf16 bf16x8  __attribute__((ext_vector_type(8)));

__device__ inline short f2bf(float f) {
    unsigned u = __builtin_bit_cast(unsigned, f);
    u += 0x7fffu + ((u >> 16) & 1u);        // round-to-nearest-even
    return (short)(u >> 16);
}
__device__ inline float bf2f(short s) {
    unsigned u = ((unsigned)(unsigned short)s) << 16;
    return __builtin_bit_cast(float, u);
}

// ---------------------------------------------------------------------------
// Reformat W_up / W_hidden into MFMA B-fragment-major bf16.
// frag g = (ks*16 + nt)*64 + lane holds W[ks*32+(lane>>4)*8+j][nt*16+(lane&15)]
// ---------------------------------------------------------------------------
__global__ __launch_bounds__(256) void prep_weights(
    const float* __restrict__ wup, const float* __restrict__ whid,
    short* __restrict__ wfrag)
{
    int g   = blockIdx.x * 256 + threadIdx.x;   // 0..65535
    int mat = g >> 13;
    int grp = g & 8191;
    int a = mat >> 2, lay = mat & 3;
    const float* src = (lay == 0) ? (wup + a * 65536)
                                  : (whid + (a * 3 + lay - 1) * 65536);
    int ks  = grp >> 10;
    int rem = grp & 1023;
    int ntg = rem >> 6;
    int lane = rem & 63;
    int q = lane >> 4, c = lane & 15;
    int col = ntg * 16 + c;
    int k0  = ks * 32 + q * 8;
    shortx8 v;
#pragma unroll
    for (int j = 0; j < 8; j++) v[j] = f2bf(src[(k0 + j) * 256 + col]);
    ((shortx8*)wfrag)[g] = v;
}

// ---------------------------------------------------------------------------
// CSR build: histogram -> exclusive scan -> id scatter.
// ---------------------------------------------------------------------------
__global__ __launch_bounds__(256) void hist_kernel(
    const int* __restrict__ idx, int* __restrict__ counts)
{
    int e = blockIdx.x * 256 + threadIdx.x;
    if (e < E_EDGES) atomicAdd(&counts[idx[e]], 1);
}

__global__ __launch_bounds__(1024) void scan_kernel(
    const int* __restrict__ counts, int* __restrict__ offsets,
    int* __restrict__ cursor)
{
    const int t = threadIdx.x;                  // 1024 threads, chunk = 30
    const int lane = t & 63, wave = t >> 6;
    const int base = t * 30;
    int local[30];
    int s = 0;
#pragma unroll
    for (int j = 0; j < 30; j++) {
        int c = (base + j < N_NODES) ? counts[base + j] : 0;
        local[j] = s;
        s += c;
    }
    int incl = s;
#pragma unroll
    for (int d = 1; d < 64; d <<= 1) {
        int v = __shfl_up(incl, d);
        if (lane >= d) incl += v;
    }
    __shared__ int part[16];
    if (lane == 63) part[wave] = incl;
    __syncthreads();
    if (t == 0) {
        int run = 0;
#pragma unroll
        for (int k = 0; k < 16; k++) { int v = part[k]; part[k] = run; run += v; }
    }
    __syncthreads();
    int excl = part[wave] + incl - s;
#pragma unroll
    for (int j = 0; j < 30; j++) {
        int n = base + j;
        if (n < N_NODES) { offsets[n] = excl + local[j]; cursor[n] = excl + local[j]; }
    }
    if (t == 1023) offsets[N_NODES] = excl + s;
}

__global__ __launch_bounds__(256) void scatter_ids(
    const int* __restrict__ idx, int* __restrict__ cursor,
    int* __restrict__ edge_list)
{
    int e = blockIdx.x * 256 + threadIdx.x;
    if (e >= E_EDGES) return;
    int pos = atomicAdd(&cursor[idx[e]], 1);
    edge_list[pos] = e;
}

// ---------------------------------------------------------------------------
// Gather: one wave per node; edge id prefetched one iteration ahead so the
// x-row load of iter j overlaps the id load of iter j+1. Nontemporal x reads
// (streamed, zero reuse) keep L2 for weights/h.
// ---------------------------------------------------------------------------
__global__ __launch_bounds__(256) void gather_nodes(
    const float* __restrict__ x, const float* __restrict__ rbf,
    const int* __restrict__ edge_list, const int* __restrict__ offsets,
    const float* __restrict__ wrbf, float* __restrict__ h)
{
    int node = blockIdx.x * 4 + (threadIdx.x >> 6);
    if (node >= N_NODES) return;
    int lane = threadIdx.x & 63;

    const floatx4* wr4 = (const floatx4*)wrbf;   // [6][64] float4
    floatx4 wr[6];
#pragma unroll
    for (int k = 0; k < 6; k++) wr[k] = wr4[k * 64 + lane];

    int beg = offsets[node], end = offsets[node + 1];
    floatx4 acc = {0.f, 0.f, 0.f, 0.f};
    if (beg < end) {
        int e = edge_list[beg];
        for (int j = beg; j < end; j++) {
            int e_next = (j + 1 < end) ? edge_list[j + 1] : e;
            floatx4 xv = __builtin_nontemporal_load(
                             (const floatx4*)x + (size_t)e * 64 + lane);
            float r0 = rbf[e * 6 + 0], r1 = rbf[e * 6 + 1], r2 = rbf[e * 6 + 2];
            float r3 = rbf[e * 6 + 3], r4 = rbf[e * 6 + 4], r5 = rbf[e * 6 + 5];
            floatx4 p = r0 * wr[0] + r1 * wr[1] + r2 * wr[2]
                      + r3 * wr[3] + r4 * wr[4] + r5 * wr[5];
            acc += p * xv;
            e = e_next;
        }
    }
    ((floatx4*)h)[(size_t)node * 64 + lane] = acc;
}

// ---------------------------------------------------------------------------
// Fused MLP v2: single LDS buffer (33.8 KB -> 4 blocks/CU), 16B staging
// writes, vectorized final dot. Block = 64 rows, wave w owns cols [64w,64w+64).
// ---------------------------------------------------------------------------
__global__ __launch_bounds__(256, 4) void mlp_kernel(
    const float* __restrict__ h, const short* __restrict__ wfrag,
    const float* __restrict__ bias, const float* __restrict__ wout,
    float* __restrict__ out)
{
    __shared__ __align__(16) short ylds[64 * 264];
    const int t = threadIdx.x;
    const int wave = t >> 6, lane = t & 63, q = lane >> 4, c15 = lane & 15;
    const int n0 = blockIdx.x * 64;
    const floatx4 fzero = {0.f, 0.f, 0.f, 0.f};

    for (int a = 0; a < 2; a++) {
        // stage h tile -> ylds as bf16, 16 B per thread per iteration
#pragma unroll
        for (int j = 0; j < 8; j++) {
            int f = t + j * 256;            // unit = 8 cols
            int r = f >> 5, c8 = f & 31;
            floatx4 v0 = fzero, v1 = fzero;
            if (n0 + r < N_NODES) {
                v0 = ((const floatx4*)h)[(size_t)(n0 + r) * 64 + c8 * 2];
                v1 = ((const floatx4*)h)[(size_t)(n0 + r) * 64 + c8 * 2 + 1];
            }
            shortx8 s8 = { f2bf(v0.x), f2bf(v0.y), f2bf(v0.z), f2bf(v0.w),
                           f2bf(v1.x), f2bf(v1.y), f2bf(v1.z), f2bf(v1.w) };
            *(shortx8*)&ylds[r * 264 + c8 * 8] = s8;
        }
        __syncthreads();

        for (int lay = 0; lay < 4; lay++) {     // 0 = up (no bias/act), 1..3 hidden
            const bf16x8* wf = (const bf16x8*)(wfrag + (size_t)(a * 4 + lay) * 65536);
            floatx4 acc[4][4];
#pragma unroll
            for (int mt = 0; mt < 4; mt++)
#pragma unroll
                for (int nt = 0; nt < 4; nt++) acc[mt][nt] = fzero;

#pragma unroll
            for (int ks = 0; ks < 8; ks++) {
                bf16x8 bfr[4];
#pragma unroll
                for (int nt = 0; nt < 4; nt++)
                    bfr[nt] = wf[(ks * 16 + wave * 4 + nt) * 64 + lane];
#pragma unroll
                for (int mt = 0; mt < 4; mt++) {
                    bf16x8 afr = *(const bf16x8*)&ylds[(mt * 16 + c15) * 264 + ks * 32 + q * 8];
#pragma unroll
                    for (int nt = 0; nt < 4; nt++)
                        acc[mt][nt] = __builtin_amdgcn_mfma_f32_16x16x32_bf16(
                            afr, bfr[nt], acc[mt][nt], 0, 0, 0);
                }
            }
            __syncthreads();                    // all reads done before overwrite

            float bv[4];
#pragma unroll
            for (int nt = 0; nt < 4; nt++)
                bv[nt] = (lay >= 1) ? bias[(a * 3 + lay - 1) * 256 + wave * 64 + nt * 16 + c15]
                                    : 0.0f;
#pragma unroll
            for (int mt = 0; mt < 4; mt++) {
#pragma unroll
                for (int nt = 0; nt < 4; nt++) {
#pragma unroll
                    for (int rg = 0; rg < 4; rg++) {
                        float v = acc[mt][nt][rg] + bv[nt];
                        if (lay >= 1) v = v / (1.0f + __expf(-v));   // SiLU
                        int row = mt * 16 + q * 4 + rg;              // D: row = quad*4+reg
                        int col = wave * 64 + nt * 16 + c15;         // D: col = lane&15
                        ylds[row * 264 + col] = f2bf(v);
                    }
                }
            }
            __syncthreads();
        }

        // out = y @ W_out[a]: wave w rows [16w,16w+16), 4 lanes per row
        {
            int r  = wave * 16 + (lane >> 2);
            int cq = lane & 3;
            const floatx4* w4 = (const floatx4*)(wout + a * 256);
            float s = 0.0f;
#pragma unroll
            for (int b8 = 0; b8 < 8; b8++) {
                shortx8 yv = *(const shortx8*)&ylds[r * 264 + cq * 64 + b8 * 8];
                floatx4 w0 = w4[cq * 16 + b8 * 2];
                floatx4 w1 = w4[cq * 16 + b8 * 2 + 1];
                s += bf2f(yv[0]) * w0.x + bf2f(yv[1]) * w0.y
                   + bf2f(yv[2]) * w0.z + bf2f(yv[3]) * w0.w
                   + bf2f(yv[4]) * w1.x + bf2f(yv[5]) * w1.y
                   + bf2f(yv[6]) * w1.z + bf2f(yv[7]) * w1.w;
            }
            s += __shfl_xor(s, 1);
            s += __shfl_xor(s, 2);
            if (cq == 0 && n0 + r < N_NODES) out[a * N_NODES + n0 + r] = s;
        }
        __syncthreads();
    }
}

// ---------------------------------------------------------------------------
extern "C" void kernel_launch(void* const* d_in, const int* in_sizes, int n_in,
                              void* d_out, int out_size, void* d_ws, size_t ws_size,
                              hipStream_t stream)
{
    const float* x    = (const float*)d_in[0];
    const float* rbf  = (const float*)d_in[1];
    const int*   idx  = (const int*)d_in[2];
    const float* wrbf = (const float*)d_in[4];
    const float* wup  = (const float*)d_in[5];
    const float* whid = (const float*)d_in[6];
    const float* bias = (const float*)d_in[7];
    const float* wout = (const float*)d_in[8];
    float* out = (float*)d_out;

    char* ws = (char*)d_ws;
    float* h         = (float*)ws;     ws += (size_t)N_NODES * H_DIM * sizeof(float);
    short* wfrag     = (short*)ws;     ws += (size_t)8 * 65536 * sizeof(short);
    int*   counts    = (int*)ws;       ws += (size_t)N_NODES * sizeof(int);
    int*   offsets   = (int*)ws;       ws += (size_t)(N_NODES + 1) * sizeof(int);
    int*   cursor    = (int*)ws;       ws += (size_t)N_NODES * sizeof(int);
    int*   edge_list = (int*)ws;

    hipMemsetAsync(counts, 0, (size_t)N_NODES * sizeof(int), stream);
    prep_weights<<<256, 256, 0, stream>>>(wup, whid, wfrag);
    hist_kernel<<<(E_EDGES + 255) / 256, 256, 0, stream>>>(idx, counts);
    scan_kernel<<<1, 1024, 0, stream>>>(counts, offsets, cursor);
    scatter_ids<<<(E_EDGES + 255) / 256, 256, 0, stream>>>(idx, cursor, edge_list);
    gather_nodes<<<(N_NODES + 3) / 4, 256, 0, stream>>>(x, rbf, edge_list, offsets, wrbf, h);
    mlp_kernel<<<(N_NODES + 63) / 64, 256, 0, stream>>>(h, wfrag, bias, wout, out);
}